// Round 10
// baseline (193.867 us; speedup 1.0000x reference)
//
#include <hip/hip_runtime.h>
#include <math.h>

#define BB 2
#define TT 2048
#define CC 1024
#define UU 1024
#define HH 16
#define DH 64
#define BT (BB*TT)

typedef __attribute__((ext_vector_type(8))) __bf16 bf16x8;
typedef __attribute__((ext_vector_type(4))) __bf16 bf16x4;
typedef __attribute__((ext_vector_type(4))) float f32x4;

#define GLL16(g, l) __builtin_amdgcn_global_load_lds( \
    (__attribute__((address_space(1))) const void*)(g), \
    (__attribute__((address_space(3))) void*)(l), 16, 0, 0)

// log2(e)/8 : folds the 1/sqrt(dh) scale and the exp->exp2 conversion
#define C2EXP 0.18033688011112042f
#define MBIAS 64.0f

// ---------------- fused prep: rowsum-mask + x cast  |  W cast+transpose ----------------
__global__ __launch_bounds__(256) void prep_kernel(
    const float* __restrict__ x, float* __restrict__ kadd, __bf16* __restrict__ xb,
    const float* __restrict__ Wq, const float* __restrict__ Wk,
    const float* __restrict__ Wv, __bf16* __restrict__ Wt) {
    const int bx = blockIdx.x;
    const int t = threadIdx.x;
    if (bx < BT) {
        int row = bx;
        float4 v = *(const float4*)&x[(size_t)row * CC + t * 4];
        bf16x4 o;
        o[0] = (__bf16)v.x; o[1] = (__bf16)v.y; o[2] = (__bf16)v.z; o[3] = (__bf16)v.w;
        *(bf16x4*)&xb[(size_t)row * CC + t * 4] = o;
        float s = v.x + v.y + v.z + v.w;
#pragma unroll
        for (int off = 32; off; off >>= 1) s += __shfl_down(s, off, 64);
        __shared__ float red[4];
        int lane = t & 63, w = t >> 6;
        if (lane == 0) red[w] = s;
        __syncthreads();
        if (t == 0) {
            float tot = red[0] + red[1] + red[2] + red[3];
            kadd[row] = (tot == 0.f ? -1.0e30f : 0.f) - MBIAS;
        }
    } else {
        int bz = bx - BT;
        int z = bz >> 8, rem = bz & 255;
        const float* W = z == 0 ? Wq : (z == 1 ? Wk : Wv);
        __bf16* Out = Wt + (size_t)z * CC * UU;
        __shared__ float tile[64][65];
        int n0 = (rem & 15) * 64, k0 = (rem >> 4) * 64;
        int r = t >> 4, c4 = (t & 15) * 4;
#pragma unroll
        for (int i = 0; i < 4; ++i) {
            float4 v = *(const float4*)&W[(size_t)(k0 + r + i * 16) * UU + n0 + c4];
            tile[r + i * 16][c4 + 0] = v.x; tile[r + i * 16][c4 + 1] = v.y;
            tile[r + i * 16][c4 + 2] = v.z; tile[r + i * 16][c4 + 3] = v.w;
        }
        __syncthreads();
#pragma unroll
        for (int i = 0; i < 4; ++i) {
            int nr = r + i * 16;
            bf16x4 o;
            o[0] = (__bf16)tile[c4 + 0][nr]; o[1] = (__bf16)tile[c4 + 1][nr];
            o[2] = (__bf16)tile[c4 + 2][nr]; o[3] = (__bf16)tile[c4 + 3][nr];
            *(bf16x4*)&Out[(size_t)(n0 + nr) * CC + k0 + c4] = o;
        }
    }
}

// ---------------- QKV GEMM, bf16 MFMA, BK=64, XOR-swizzled LDS ----------------
__global__ __launch_bounds__(256, 4) void qkv_mfma(
    const __bf16* __restrict__ xb, const __bf16* __restrict__ Wt_all,
    const float* __restrict__ bq, const float* __restrict__ bk,
    const float* __restrict__ bv,
    __bf16* __restrict__ Qo, __bf16* __restrict__ Ko, __bf16* __restrict__ VTo) {
    const int z = blockIdx.z;
    const __bf16* Wt = Wt_all + (size_t)z * CC * UU;
    const float* bias = z == 0 ? bq : (z == 1 ? bk : bv);

    const int n0 = blockIdx.x * 128, m0 = blockIdx.y * 128;
    const int t = threadIdx.x, w = t >> 6, lane = t & 63;
    const int quad = lane >> 4, nn = lane & 15;
    const int wr = w >> 1, wc = w & 1;

    __shared__ __bf16 smem[2 * 128 * 64];
    __bf16* As = smem;
    __bf16* Bs = smem + 128 * 64;

    f32x4 acc[4][4];
#pragma unroll
    for (int i = 0; i < 4; ++i)
#pragma unroll
        for (int j = 0; j < 4; ++j) acc[i][j] = (f32x4){0.f, 0.f, 0.f, 0.f};

    for (int k0 = 0; k0 < CC; k0 += 64) {
        __syncthreads();
#pragma unroll
        for (int i = 0; i < 4; ++i) {
            int c = i * 256 + t;
            int row = c >> 3;
            int gc = ((c & 7) ^ (row & 7)) * 8;
            GLL16(&xb[(size_t)(m0 + row) * CC + k0 + gc], &As[c * 8]);
            GLL16(&Wt[(size_t)(n0 + row) * CC + k0 + gc], &Bs[c * 8]);
        }
        __syncthreads();
#pragma unroll
        for (int kk = 0; kk < 2; ++kk) {
            bf16x8 af[4], bfr[4];
#pragma unroll
            for (int i = 0; i < 4; ++i) {
                int R = wr * 64 + i * 16 + nn;
                af[i] = *(const bf16x8*)&As[R * 64 + (((kk * 4 + quad) ^ (R & 7)) * 8)];
            }
#pragma unroll
            for (int j = 0; j < 4; ++j) {
                int R = wc * 64 + j * 16 + nn;
                bfr[j] = *(const bf16x8*)&Bs[R * 64 + (((kk * 4 + quad) ^ (R & 7)) * 8)];
            }
#pragma unroll
            for (int i = 0; i < 4; ++i)
#pragma unroll
                for (int j = 0; j < 4; ++j)
                    acc[i][j] = __builtin_amdgcn_mfma_f32_16x16x32_bf16(af[i], bfr[j], acc[i][j], 0, 0, 0);
        }
    }

    __bf16* cw = &smem[w * 1024];
    float bv4[4];
#pragma unroll
    for (int j = 0; j < 4; ++j) bv4[j] = bias[n0 + wc * 64 + j * 16 + nn];

    if (z < 2) {
        __bf16* Out = z == 0 ? Qo : Ko;
#pragma unroll
        for (int i = 0; i < 4; ++i) {
            __syncthreads();
#pragma unroll
            for (int j = 0; j < 4; ++j)
#pragma unroll
                for (int r = 0; r < 4; ++r)
                    cw[(quad * 4 + r) * 64 + j * 16 + nn] =
                        (__bf16)fmaxf(acc[i][j][r] + bv4[j], 0.f);
            __syncthreads();
            int rr = lane >> 2, cc = (lane & 3) * 16;
            bf16x8 v0 = *(const bf16x8*)&cw[rr * 64 + cc];
            bf16x8 v1 = *(const bf16x8*)&cw[rr * 64 + cc + 8];
            size_t o = (size_t)(m0 + wr * 64 + i * 16 + rr) * UU + n0 + wc * 64 + cc;
            *(bf16x8*)&Out[o] = v0;
            *(bf16x8*)&Out[o + 8] = v1;
        }
    } else {
#pragma unroll
        for (int i = 0; i < 4; ++i) {
            __syncthreads();
#pragma unroll
            for (int j = 0; j < 4; ++j)
#pragma unroll
                for (int r = 0; r < 4; ++r)
                    cw[(j * 16 + nn) * 16 + quad * 4 + r] =
                        (__bf16)fmaxf(acc[i][j][r] + bv4[j], 0.f);
            __syncthreads();
            bf16x8 v0 = *(const bf16x8*)&cw[lane * 16];
            bf16x8 v1 = *(const bf16x8*)&cw[lane * 16 + 8];
            size_t o = (size_t)(n0 + wc * 64 + lane) * BT + m0 + wr * 64 + i * 16;
            *(bf16x8*)&VTo[o] = v0;
            *(bf16x8*)&VTo[o + 8] = v1;
        }
    }
}

// ---------------- MFMA flash attention: 128-q blocks, 2 strips/wave ----------------
// grid (bh=32, y=16): qt2 = y<8 ? y : 23-y  -> same-CU pairs (y,y+8) sum to
// constant work (34 k-tiles). Wave w owns q rows [32w,32w+32) as 2 strips of 16.
// K/V fragments shared by both strips (LDS reads/MFMA -40%); kadd loads issued
// BEFORE prefetch GLLs; fully-masked strip-tiles skipped (wave-uniform branch).
// LDS: ps 16K + ks 2x8K + vt 2x8K = 48 KiB; 512 blocks = 2/CU all resident.
__global__ __launch_bounds__(256, 2) void attn_mfma(
    const __bf16* __restrict__ Q, const __bf16* __restrict__ K,
    const __bf16* __restrict__ Vt, const float* __restrict__ kadd,
    __bf16* __restrict__ Ob) {
    const int yy = blockIdx.y;
    const int qt2 = (yy < 8) ? yy : 23 - yy;
    const int bh = blockIdx.x, b = bh >> 4, h = bh & 15;
    const int col0 = h * 64, rowbase = b * TT, q0 = qt2 * 128;

    const int t = threadIdx.x;
    const int w = t >> 6, lane = t & 63, quad = lane >> 4, nn = lane & 15;
    const int s7 = nn & 7;

    __shared__ __align__(16) __bf16 ks[2][64 * 64];
    __shared__ __align__(16) __bf16 vt[2][64 * 64];
    __shared__ __align__(16) __bf16 ps[128 * 64];   // Q staging, then P (wave-private rows)

    const int c0 = t, c1 = 256 + t;
    const int r0 = c0 >> 3, g0 = ((c0 & 7) ^ (r0 & 7)) * 8;
    const int r1 = c1 >> 3, g1 = ((c1 & 7) ^ (r1 & 7)) * 8;

    // stage Q (128x64, swizzled) + first K/V tile (buffer 0)
#pragma unroll
    for (int i = 0; i < 4; ++i) {
        int c = i * 256 + t;
        int r = c >> 3, g = ((c & 7) ^ (r & 7)) * 8;
        GLL16(&Q[(size_t)(rowbase + q0 + r) * UU + col0 + g], &ps[c * 8]);
    }
    GLL16(&K[(size_t)(rowbase + r0) * UU + col0 + g0], &ks[0][c0 * 8]);
    GLL16(&K[(size_t)(rowbase + r1) * UU + col0 + g1], &ks[0][c1 * 8]);
    GLL16(&Vt[(size_t)(col0 + r0) * BT + rowbase + g0], &vt[0][c0 * 8]);
    GLL16(&Vt[(size_t)(col0 + r1) * BT + rowbase + g1], &vt[0][c1 * 8]);
    __syncthreads();   // vmcnt drain: Q + tile 0 visible

    // Q B-fragments (q = n operand), wave-private rows 32w+16s+nn
    bf16x8 bq[2][2];
    int prow[2];
#pragma unroll
    for (int s = 0; s < 2; ++s) {
        prow[s] = 32 * w + 16 * s + nn;
        int p7 = prow[s] & 7;
        bq[s][0] = *(const bf16x8*)&ps[prow[s] * 64 + ((quad ^ p7) * 8)];
        bq[s][1] = *(const bf16x8*)&ps[prow[s] * 64 + (((4 + quad) ^ p7) * 8)];
    }

    float lp[2] = {0.f, 0.f};
    f32x4 oc[2][4];
#pragma unroll
    for (int s = 0; s < 2; ++s)
#pragma unroll
        for (int dt = 0; dt < 4; ++dt) oc[s][dt] = (f32x4){0.f, 0.f, 0.f, 0.f};

    const int nkt = 2 * qt2 + 2;
    for (int kt = 0; kt < nkt; ++kt) {
        const int cur = kt & 1;
        const int k0 = kt * 64;
        // kadd loads FIRST (their wait leaves the prefetch in flight)
        f32x4 ka[4];
#pragma unroll
        for (int ct = 0; ct < 4; ++ct)
            ka[ct] = *(const f32x4*)&kadd[rowbase + k0 + ct * 16 + quad * 4];
        // prefetch next K/V tile into the other buffer
        if (kt + 1 < nkt) {
            const int kn = k0 + 64;
            GLL16(&K[(size_t)(rowbase + kn + r0) * UU + col0 + g0], &ks[cur ^ 1][c0 * 8]);
            GLL16(&K[(size_t)(rowbase + kn + r1) * UU + col0 + g1], &ks[cur ^ 1][c1 * 8]);
            GLL16(&Vt[(size_t)(col0 + r0) * BT + rowbase + kn + g0], &vt[cur ^ 1][c0 * 8]);
            GLL16(&Vt[(size_t)(col0 + r1) * BT + rowbase + kn + g1], &vt[cur ^ 1][c1 * 8]);
        }

        const __bf16* ksc = ks[cur];
        const __bf16* vtc = vt[cur];

        // K A-fragments, shared by both strips
        bf16x8 kf[4][2];
#pragma unroll
        for (int ct = 0; ct < 4; ++ct) {
            int krow = ct * 16 + nn;
            kf[ct][0] = *(const bf16x8*)&ksc[krow * 64 + ((quad ^ s7) * 8)];
            kf[ct][1] = *(const bf16x8*)&ksc[krow * 64 + (((4 + quad) ^ s7) * 8)];
        }

        bool live[2];
        bf16x8 bp[2][2];
#pragma unroll
        for (int s = 0; s < 2; ++s) {
            const int qsb = q0 + 32 * w + 16 * s;      // strip q-base
            live[s] = (k0 <= qsb + 15);                // wave-uniform
            if (!live[s]) continue;
            const int qg = qsb + nn;
            const bool needmask = (k0 + 63) > qsb;
            const int p7 = prow[s] & 7;
            // S^T = K·Q^T : lane holds keys ct*16+quad*4+r at q=qg
#pragma unroll
            for (int ct = 0; ct < 4; ++ct) {
                f32x4 sc = (f32x4){0.f, 0.f, 0.f, 0.f};
                sc = __builtin_amdgcn_mfma_f32_16x16x32_bf16(kf[ct][0], bq[s][0], sc, 0, 0, 0);
                sc = __builtin_amdgcn_mfma_f32_16x16x32_bf16(kf[ct][1], bq[s][1], sc, 0, 0, 0);
                bf16x4 pw;
#pragma unroll
                for (int r = 0; r < 4; ++r) {
                    int key = k0 + ct * 16 + quad * 4 + r;
                    float arg = fmaf(sc[r], C2EXP, ka[ct][r]);
                    if (needmask && key > qg) arg = -1.0e30f;
                    float p = exp2f(arg);
                    lp[s] += p;
                    pw[r] = (__bf16)p;
                }
                int chunk = ct * 2 + (quad >> 1);
                *(bf16x4*)&ps[prow[s] * 64 + ((chunk ^ p7) * 8) + (quad & 1) * 4] = pw;
            }
            // P B-fragments (wave-private rows; same-wave DS ordering)
            bp[s][0] = *(const bf16x8*)&ps[prow[s] * 64 + ((quad ^ p7) * 8)];
            bp[s][1] = *(const bf16x8*)&ps[prow[s] * 64 + (((4 + quad) ^ p7) * 8)];
        }
        // O^T = V^T·P^T : V fragments shared by both strips (dt-outer)
#pragma unroll
        for (int dt = 0; dt < 4; ++dt) {
            int vrow = dt * 16 + nn;
            bf16x8 v0 = *(const bf16x8*)&vtc[vrow * 64 + ((quad ^ s7) * 8)];
            bf16x8 v1 = *(const bf16x8*)&vtc[vrow * 64 + (((4 + quad) ^ s7) * 8)];
#pragma unroll
            for (int s = 0; s < 2; ++s) {
                if (!live[s]) continue;
                oc[s][dt] = __builtin_amdgcn_mfma_f32_16x16x32_bf16(v0, bp[s][0], oc[s][dt], 0, 0, 0);
                oc[s][dt] = __builtin_amdgcn_mfma_f32_16x16x32_bf16(v1, bp[s][1], oc[s][dt], 0, 0, 0);
            }
        }
        __syncthreads();   // all waves done with buf[cur]; own prefetch drained
    }

    // epilogue: l across quads (disjoint key quarters), /l, query mask, bf16 stores
#pragma unroll
    for (int s = 0; s < 2; ++s) {
        float l = lp[s];
        l += __shfl_xor(l, 16, 64);
        l += __shfl_xor(l, 32, 64);
        int grow = rowbase + q0 + 32 * w + 16 * s + nn;
        float qsel = (kadd[grow] < -1.0e29f) ? 0.f : 1.f;
        float mult = qsel / fmaxf(l, 1e-37f);
#pragma unroll
        for (int dt = 0; dt < 4; ++dt) {
            bf16x4 ov;
            ov[0] = (__bf16)(oc[s][dt][0] * mult); ov[1] = (__bf16)(oc[s][dt][1] * mult);
            ov[2] = (__bf16)(oc[s][dt][2] * mult); ov[3] = (__bf16)(oc[s][dt][3] * mult);
            *(bf16x4*)&Ob[(size_t)grow * UU + col0 + dt * 16 + quad * 4] = ov;
        }
    }
}

// ---------------- residual + layernorm (bf16 attention input) ----------------
__global__ __launch_bounds__(256) void ln_kernel(
    const __bf16* __restrict__ Ob, const float* __restrict__ x,
    const float* __restrict__ gamma, const float* __restrict__ beta,
    float* __restrict__ out) {
    int row = blockIdx.x;
    size_t base = (size_t)row * UU;
    int t = threadIdx.x;
    bf16x4 ov = *(const bf16x4*)&Ob[base + t * 4];
    float4 xv = *(const float4*)&x[base + t * 4];
    float v0 = (float)ov[0] + xv.x, v1 = (float)ov[1] + xv.y;
    float v2 = (float)ov[2] + xv.z, v3 = (float)ov[3] + xv.w;
    float s1 = v0 + v1 + v2 + v3;
    float s2 = v0 * v0 + v1 * v1 + v2 * v2 + v3 * v3;
#pragma unroll
    for (int off = 32; off; off >>= 1) {
        s1 += __shfl_down(s1, off, 64);
        s2 += __shfl_down(s2, off, 64);
    }
    __shared__ float r1[4], r2[4];
    int lane = t & 63, w = t >> 6;
    if (lane == 0) { r1[w] = s1; r2[w] = s2; }
    __syncthreads();
    s1 = r1[0] + r1[1] + r1[2] + r1[3];
    s2 = r2[0] + r2[1] + r2[2] + r2[3];
    float mean = s1 * (1.0f / 1024.0f);
    float var = s2 * (1.0f / 1024.0f) - mean * mean;
    float rstd = rsqrtf(var + 1e-8f);
    float4 g = *(const float4*)&gamma[t * 4];
    float4 be = *(const float4*)&beta[t * 4];
    float4 ores;
    ores.x = g.x * (v0 - mean) * rstd + be.x;
    ores.y = g.y * (v1 - mean) * rstd + be.y;
    ores.z = g.z * (v2 - mean) * rstd + be.z;
    ores.w = g.w * (v3 - mean) * rstd + be.w;
    *(float4*)&out[base + t * 4] = ores;
}

extern "C" void kernel_launch(void* const* d_in, const int* in_sizes, int n_in,
                              void* d_out, int out_size, void* d_ws, size_t ws_size,
                              hipStream_t stream) {
    const float* x     = (const float*)d_in[0];
    const float* Wq    = (const float*)d_in[1];
    const float* bq    = (const float*)d_in[2];
    const float* Wk    = (const float*)d_in[3];
    const float* bk    = (const float*)d_in[4];
    const float* Wv    = (const float*)d_in[5];
    const float* bv    = (const float*)d_in[6];
    const float* gamma = (const float*)d_in[7];
    const float* beta  = (const float*)d_in[8];
    float* out = (float*)d_out;

    char* wsb = (char*)d_ws;
    const size_t MB = 1024ull * 1024;
    __bf16* xb = (__bf16*)(wsb);                 // 0..8 MiB   (dead after qkv)
    __bf16* Wt = (__bf16*)(wsb + 8 * MB);        // 8..14 MiB  (dead after qkv)
    __bf16* Ob = (__bf16*)(wsb);                 // 0..8 MiB   (aliases xb)
    __bf16* Qb = (__bf16*)(wsb + 16 * MB);       // 8 MiB
    __bf16* Kb = (__bf16*)(wsb + 24 * MB);       // 8 MiB
    __bf16* Vt = (__bf16*)(wsb + 32 * MB);       // 8 MiB
    float* kadd = (float*)(wsb + 40 * MB);       // 16 KiB

    prep_kernel<<<dim3(BT + 768), dim3(256), 0, stream>>>(x, kadd, xb, Wq, Wk, Wv, Wt);
    qkv_mfma<<<dim3(UU / 128, BT / 128, 3), dim3(256), 0, stream>>>(
        xb, Wt, bq, bk, bv, Qb, Kb, Vt);
    attn_mfma<<<dim3(BB * HH, 16), dim3(256), 0, stream>>>(Qb, Kb, Vt, kadd, Ob);
    ln_kernel<<<dim3(BT), dim3(256), 0, stream>>>(Ob, x, gamma, beta, out);
}

// Round 11
// 172.119 us; speedup vs baseline: 1.1264x; 1.1264x over previous
//
#include <hip/hip_runtime.h>
#include <math.h>

#define BB 2
#define TT 2048
#define CC 1024
#define UU 1024
#define HH 16
#define DH 64
#define BT (BB*TT)

typedef __attribute__((ext_vector_type(8))) __bf16 bf16x8;
typedef __attribute__((ext_vector_type(4))) __bf16 bf16x4;
typedef __attribute__((ext_vector_type(4))) float f32x4;

#define GLL16(g, l) __builtin_amdgcn_global_load_lds( \
    (__attribute__((address_space(1))) const void*)(g), \
    (__attribute__((address_space(3))) void*)(l), 16, 0, 0)

// log2(e)/8 : folds the 1/sqrt(dh) scale and the exp->exp2 conversion
#define C2EXP 0.18033688011112042f
#define MBIAS 64.0f

// ---------------- fused prep: rowsum-mask + x cast  |  W cast+transpose ----------------
__global__ __launch_bounds__(256) void prep_kernel(
    const float* __restrict__ x, float* __restrict__ kadd, __bf16* __restrict__ xb,
    const float* __restrict__ Wq, const float* __restrict__ Wk,
    const float* __restrict__ Wv, __bf16* __restrict__ Wt) {
    const int bx = blockIdx.x;
    const int t = threadIdx.x;
    if (bx < BT) {
        int row = bx;
        float4 v = *(const float4*)&x[(size_t)row * CC + t * 4];
        bf16x4 o;
        o[0] = (__bf16)v.x; o[1] = (__bf16)v.y; o[2] = (__bf16)v.z; o[3] = (__bf16)v.w;
        *(bf16x4*)&xb[(size_t)row * CC + t * 4] = o;
        float s = v.x + v.y + v.z + v.w;
#pragma unroll
        for (int off = 32; off; off >>= 1) s += __shfl_down(s, off, 64);
        __shared__ float red[4];
        int lane = t & 63, w = t >> 6;
        if (lane == 0) red[w] = s;
        __syncthreads();
        if (t == 0) {
            float tot = red[0] + red[1] + red[2] + red[3];
            kadd[row] = (tot == 0.f ? -1.0e30f : 0.f) - MBIAS;
        }
    } else {
        int bz = bx - BT;
        int z = bz >> 8, rem = bz & 255;
        const float* W = z == 0 ? Wq : (z == 1 ? Wk : Wv);
        __bf16* Out = Wt + (size_t)z * CC * UU;
        __shared__ float tile[64][65];
        int n0 = (rem & 15) * 64, k0 = (rem >> 4) * 64;
        int r = t >> 4, c4 = (t & 15) * 4;
#pragma unroll
        for (int i = 0; i < 4; ++i) {
            float4 v = *(const float4*)&W[(size_t)(k0 + r + i * 16) * UU + n0 + c4];
            tile[r + i * 16][c4 + 0] = v.x; tile[r + i * 16][c4 + 1] = v.y;
            tile[r + i * 16][c4 + 2] = v.z; tile[r + i * 16][c4 + 3] = v.w;
        }
        __syncthreads();
#pragma unroll
        for (int i = 0; i < 4; ++i) {
            int nr = r + i * 16;
            bf16x4 o;
            o[0] = (__bf16)tile[c4 + 0][nr]; o[1] = (__bf16)tile[c4 + 1][nr];
            o[2] = (__bf16)tile[c4 + 2][nr]; o[3] = (__bf16)tile[c4 + 3][nr];
            *(bf16x4*)&Out[(size_t)(n0 + nr) * CC + k0 + c4] = o;
        }
    }
}

// ---------------- QKV GEMM, bf16 MFMA, BK=64, XOR-swizzled LDS ----------------
__global__ __launch_bounds__(256, 4) void qkv_mfma(
    const __bf16* __restrict__ xb, const __bf16* __restrict__ Wt_all,
    const float* __restrict__ bq, const float* __restrict__ bk,
    const float* __restrict__ bv,
    __bf16* __restrict__ Qo, __bf16* __restrict__ Ko, __bf16* __restrict__ VTo) {
    const int z = blockIdx.z;
    const __bf16* Wt = Wt_all + (size_t)z * CC * UU;
    const float* bias = z == 0 ? bq : (z == 1 ? bk : bv);

    const int n0 = blockIdx.x * 128, m0 = blockIdx.y * 128;
    const int t = threadIdx.x, w = t >> 6, lane = t & 63;
    const int quad = lane >> 4, nn = lane & 15;
    const int wr = w >> 1, wc = w & 1;

    __shared__ __bf16 smem[2 * 128 * 64];
    __bf16* As = smem;
    __bf16* Bs = smem + 128 * 64;

    f32x4 acc[4][4];
#pragma unroll
    for (int i = 0; i < 4; ++i)
#pragma unroll
        for (int j = 0; j < 4; ++j) acc[i][j] = (f32x4){0.f, 0.f, 0.f, 0.f};

    for (int k0 = 0; k0 < CC; k0 += 64) {
        __syncthreads();
#pragma unroll
        for (int i = 0; i < 4; ++i) {
            int c = i * 256 + t;
            int row = c >> 3;
            int gc = ((c & 7) ^ (row & 7)) * 8;
            GLL16(&xb[(size_t)(m0 + row) * CC + k0 + gc], &As[c * 8]);
            GLL16(&Wt[(size_t)(n0 + row) * CC + k0 + gc], &Bs[c * 8]);
        }
        __syncthreads();
#pragma unroll
        for (int kk = 0; kk < 2; ++kk) {
            bf16x8 af[4], bfr[4];
#pragma unroll
            for (int i = 0; i < 4; ++i) {
                int R = wr * 64 + i * 16 + nn;
                af[i] = *(const bf16x8*)&As[R * 64 + (((kk * 4 + quad) ^ (R & 7)) * 8)];
            }
#pragma unroll
            for (int j = 0; j < 4; ++j) {
                int R = wc * 64 + j * 16 + nn;
                bfr[j] = *(const bf16x8*)&Bs[R * 64 + (((kk * 4 + quad) ^ (R & 7)) * 8)];
            }
#pragma unroll
            for (int i = 0; i < 4; ++i)
#pragma unroll
                for (int j = 0; j < 4; ++j)
                    acc[i][j] = __builtin_amdgcn_mfma_f32_16x16x32_bf16(af[i], bfr[j], acc[i][j], 0, 0, 0);
        }
    }

    __bf16* cw = &smem[w * 1024];
    float bv4[4];
#pragma unroll
    for (int j = 0; j < 4; ++j) bv4[j] = bias[n0 + wc * 64 + j * 16 + nn];

    if (z < 2) {
        __bf16* Out = z == 0 ? Qo : Ko;
#pragma unroll
        for (int i = 0; i < 4; ++i) {
            __syncthreads();
#pragma unroll
            for (int j = 0; j < 4; ++j)
#pragma unroll
                for (int r = 0; r < 4; ++r)
                    cw[(quad * 4 + r) * 64 + j * 16 + nn] =
                        (__bf16)fmaxf(acc[i][j][r] + bv4[j], 0.f);
            __syncthreads();
            int rr = lane >> 2, cc = (lane & 3) * 16;
            bf16x8 v0 = *(const bf16x8*)&cw[rr * 64 + cc];
            bf16x8 v1 = *(const bf16x8*)&cw[rr * 64 + cc + 8];
            size_t o = (size_t)(m0 + wr * 64 + i * 16 + rr) * UU + n0 + wc * 64 + cc;
            *(bf16x8*)&Out[o] = v0;
            *(bf16x8*)&Out[o + 8] = v1;
        }
    } else {
#pragma unroll
        for (int i = 0; i < 4; ++i) {
            __syncthreads();
#pragma unroll
            for (int j = 0; j < 4; ++j)
#pragma unroll
                for (int r = 0; r < 4; ++r)
                    cw[(j * 16 + nn) * 16 + quad * 4 + r] =
                        (__bf16)fmaxf(acc[i][j][r] + bv4[j], 0.f);
            __syncthreads();
            bf16x8 v0 = *(const bf16x8*)&cw[lane * 16];
            bf16x8 v1 = *(const bf16x8*)&cw[lane * 16 + 8];
            size_t o = (size_t)(n0 + wc * 64 + lane) * BT + m0 + wr * 64 + i * 16;
            *(bf16x8*)&VTo[o] = v0;
            *(bf16x8*)&VTo[o + 8] = v1;
        }
    }
}

// ---------------- MFMA flash attention: swapped operands, CU-balanced qt map ----------------
// Same-CU blocks are ids {i, i+256, i+512, i+768} -> same bx, bh differing by 8.
// Cohort j = bh>>3 remaps qt by a bijection so each CU hosts qts
// {bx, 31-bx, (bx+16)&31, (15-bx)&31} -> per-CU iteration sum is constant (66),
// vs 4x identical qt before (critical CU 128 iters -> 66).
__global__ __launch_bounds__(256, 4) void attn_mfma(
    const __bf16* __restrict__ Q, const __bf16* __restrict__ K,
    const __bf16* __restrict__ Vt, const float* __restrict__ kadd,
    __bf16* __restrict__ Ob) {
    const int bx = blockIdx.x;                // 0..31
    const int bh = blockIdx.y, b = bh >> 4, h = bh & 15;
    const int j = bh >> 3;                    // same-CU cohort index
    const int xj = (j & 2) ? ((bx + 16) & 31) : bx;
    const int qt = (j & 1) ? (31 - xj) : xj;
    const int col0 = h * 64, rowbase = b * TT, q0 = qt * 64;

    const int t = threadIdx.x;
    const int w = t >> 6, lane = t & 63, quad = lane >> 4, nn = lane & 15;
    const int s7 = nn & 7;

    __shared__ __align__(16) __bf16 ks[2][64 * 64];
    __shared__ __align__(16) __bf16 vt[2][64 * 64];
    __shared__ __align__(16) __bf16 ps[64 * 64];   // Q staging, then P (wave-private rows)

    const int c0 = t, c1 = 256 + t;
    const int r0 = c0 >> 3, g0 = ((c0 & 7) ^ (r0 & 7)) * 8;
    const int r1 = c1 >> 3, g1 = ((c1 & 7) ^ (r1 & 7)) * 8;

    // stage Q tile (swizzled) + first K/V tile (buffer 0)
    GLL16(&Q[(size_t)(rowbase + q0 + r0) * UU + col0 + g0], &ps[c0 * 8]);
    GLL16(&Q[(size_t)(rowbase + q0 + r1) * UU + col0 + g1], &ps[c1 * 8]);
    GLL16(&K[(size_t)(rowbase + r0) * UU + col0 + g0], &ks[0][c0 * 8]);
    GLL16(&K[(size_t)(rowbase + r1) * UU + col0 + g1], &ks[0][c1 * 8]);
    GLL16(&Vt[(size_t)(col0 + r0) * BT + rowbase + g0], &vt[0][c0 * 8]);
    GLL16(&Vt[(size_t)(col0 + r1) * BT + rowbase + g1], &vt[0][c1 * 8]);
    __syncthreads();   // vmcnt drain: Q + tile 0 visible

    // Q B-fragments (q = n operand), wave-private rows 16w+nn
    const int prow = 16 * w + nn;
    bf16x8 bq0 = *(const bf16x8*)&ps[prow * 64 + ((quad ^ (prow & 7)) * 8)];
    bf16x8 bq1 = *(const bf16x8*)&ps[prow * 64 + (((4 + quad) ^ (prow & 7)) * 8)];

    float lp = 0.f;
    f32x4 oc[4];
#pragma unroll
    for (int dt = 0; dt < 4; ++dt) oc[dt] = (f32x4){0.f, 0.f, 0.f, 0.f};
    const int qg = q0 + 16 * w + nn;          // this lane's global (batch-local) q row

    for (int kt = 0; kt <= qt; ++kt) {
        const int cur = kt & 1;
        const int k0 = kt * 64;
        // kadd loads FIRST (so their wait is vmcnt(4), leaving prefetch in flight)
        f32x4 ka[4];
#pragma unroll
        for (int ct = 0; ct < 4; ++ct)
            ka[ct] = *(const f32x4*)&kadd[rowbase + k0 + ct * 16 + quad * 4];
        // prefetch next K/V tile into the other buffer (overlaps this iter's compute)
        if (kt < qt) {
            const int kn = k0 + 64;
            GLL16(&K[(size_t)(rowbase + kn + r0) * UU + col0 + g0], &ks[cur ^ 1][c0 * 8]);
            GLL16(&K[(size_t)(rowbase + kn + r1) * UU + col0 + g1], &ks[cur ^ 1][c1 * 8]);
            GLL16(&Vt[(size_t)(col0 + r0) * BT + rowbase + kn + g0], &vt[cur ^ 1][c0 * 8]);
            GLL16(&Vt[(size_t)(col0 + r1) * BT + rowbase + kn + g1], &vt[cur ^ 1][c1 * 8]);
        }

        const bool diag = (kt == qt);
        const __bf16* ksc = ks[cur];
        const __bf16* vtc = vt[cur];

        // S^T = K·Q^T : lane holds keys ct*16+quad*4+r at q=qg
#pragma unroll
        for (int ct = 0; ct < 4; ++ct) {
            int krow = ct * 16 + nn;
            bf16x8 a0 = *(const bf16x8*)&ksc[krow * 64 + ((quad ^ s7) * 8)];
            bf16x8 a1 = *(const bf16x8*)&ksc[krow * 64 + (((4 + quad) ^ s7) * 8)];
            f32x4 sc = (f32x4){0.f, 0.f, 0.f, 0.f};
            sc = __builtin_amdgcn_mfma_f32_16x16x32_bf16(a0, bq0, sc, 0, 0, 0);
            sc = __builtin_amdgcn_mfma_f32_16x16x32_bf16(a1, bq1, sc, 0, 0, 0);
            bf16x4 pw;
#pragma unroll
            for (int r = 0; r < 4; ++r) {
                int key = k0 + ct * 16 + quad * 4 + r;
                float arg = fmaf(sc[r], C2EXP, ka[ct][r]);
                if (diag && key > qg) arg = -1.0e30f;
                float p = exp2f(arg);
                lp += p;
                pw[r] = (__bf16)p;
            }
            int chunk = ct * 2 + (quad >> 1);
            *(bf16x4*)&ps[prow * 64 + ((chunk ^ (prow & 7)) * 8) + (quad & 1) * 4] = pw;
        }
        // P B-fragments (wave-private rows; same-wave DS ordering, no barrier)
        bf16x8 bp0 = *(const bf16x8*)&ps[prow * 64 + ((quad ^ (prow & 7)) * 8)];
        bf16x8 bp1 = *(const bf16x8*)&ps[prow * 64 + (((4 + quad) ^ (prow & 7)) * 8)];
        // O^T = V^T·P^T : lane holds d = dt*16+quad*4+r at q=qg
#pragma unroll
        for (int dt = 0; dt < 4; ++dt) {
            int vrow = dt * 16 + nn;
            bf16x8 a0 = *(const bf16x8*)&vtc[vrow * 64 + ((quad ^ s7) * 8)];
            bf16x8 a1 = *(const bf16x8*)&vtc[vrow * 64 + (((4 + quad) ^ s7) * 8)];
            oc[dt] = __builtin_amdgcn_mfma_f32_16x16x32_bf16(a0, bp0, oc[dt], 0, 0, 0);
            oc[dt] = __builtin_amdgcn_mfma_f32_16x16x32_bf16(a1, bp1, oc[dt], 0, 0, 0);
        }
        __syncthreads();   // all waves done with buf[cur]; own prefetch drained
    }

    // epilogue: l across quads (disjoint key quarters), /l, query mask, bf16 stores
    float l = lp;
    l += __shfl_xor(l, 16, 64);
    l += __shfl_xor(l, 32, 64);
    int grow = rowbase + qg;
    float qsel = (kadd[grow] < -1.0e29f) ? 0.f : 1.f;
    float mult = qsel / fmaxf(l, 1e-37f);
#pragma unroll
    for (int dt = 0; dt < 4; ++dt) {
        bf16x4 ov;
        ov[0] = (__bf16)(oc[dt][0] * mult); ov[1] = (__bf16)(oc[dt][1] * mult);
        ov[2] = (__bf16)(oc[dt][2] * mult); ov[3] = (__bf16)(oc[dt][3] * mult);
        *(bf16x4*)&Ob[(size_t)grow * UU + col0 + dt * 16 + quad * 4] = ov;
    }
}

// ---------------- residual + layernorm (bf16 attention input) ----------------
__global__ __launch_bounds__(256) void ln_kernel(
    const __bf16* __restrict__ Ob, const float* __restrict__ x,
    const float* __restrict__ gamma, const float* __restrict__ beta,
    float* __restrict__ out) {
    int row = blockIdx.x;
    size_t base = (size_t)row * UU;
    int t = threadIdx.x;
    bf16x4 ov = *(const bf16x4*)&Ob[base + t * 4];
    float4 xv = *(const float4*)&x[base + t * 4];
    float v0 = (float)ov[0] + xv.x, v1 = (float)ov[1] + xv.y;
    float v2 = (float)ov[2] + xv.z, v3 = (float)ov[3] + xv.w;
    float s1 = v0 + v1 + v2 + v3;
    float s2 = v0 * v0 + v1 * v1 + v2 * v2 + v3 * v3;
#pragma unroll
    for (int off = 32; off; off >>= 1) {
        s1 += __shfl_down(s1, off, 64);
        s2 += __shfl_down(s2, off, 64);
    }
    __shared__ float r1[4], r2[4];
    int lane = t & 63, w = t >> 6;
    if (lane == 0) { r1[w] = s1; r2[w] = s2; }
    __syncthreads();
    s1 = r1[0] + r1[1] + r1[2] + r1[3];
    s2 = r2[0] + r2[1] + r2[2] + r2[3];
    float mean = s1 * (1.0f / 1024.0f);
    float var = s2 * (1.0f / 1024.0f) - mean * mean;
    float rstd = rsqrtf(var + 1e-8f);
    float4 g = *(const float4*)&gamma[t * 4];
    float4 be = *(const float4*)&beta[t * 4];
    float4 ores;
    ores.x = g.x * (v0 - mean) * rstd + be.x;
    ores.y = g.y * (v1 - mean) * rstd + be.y;
    ores.z = g.z * (v2 - mean) * rstd + be.z;
    ores.w = g.w * (v3 - mean) * rstd + be.w;
    *(float4*)&out[base + t * 4] = ores;
}

extern "C" void kernel_launch(void* const* d_in, const int* in_sizes, int n_in,
                              void* d_out, int out_size, void* d_ws, size_t ws_size,
                              hipStream_t stream) {
    const float* x     = (const float*)d_in[0];
    const float* Wq    = (const float*)d_in[1];
    const float* bq    = (const float*)d_in[2];
    const float* Wk    = (const float*)d_in[3];
    const float* bk    = (const float*)d_in[4];
    const float* Wv    = (const float*)d_in[5];
    const float* bv    = (const float*)d_in[6];
    const float* gamma = (const float*)d_in[7];
    const float* beta  = (const float*)d_in[8];
    float* out = (float*)d_out;

    char* wsb = (char*)d_ws;
    const size_t MB = 1024ull * 1024;
    __bf16* xb = (__bf16*)(wsb);                 // 0..8 MiB   (dead after qkv)
    __bf16* Wt = (__bf16*)(wsb + 8 * MB);        // 8..14 MiB  (dead after qkv)
    __bf16* Ob = (__bf16*)(wsb);                 // 0..8 MiB   (aliases xb)
    __bf16* Qb = (__bf16*)(wsb + 16 * MB);       // 8 MiB
    __bf16* Kb = (__bf16*)(wsb + 24 * MB);       // 8 MiB
    __bf16* Vt = (__bf16*)(wsb + 32 * MB);       // 8 MiB
    float* kadd = (float*)(wsb + 40 * MB);       // 16 KiB

    prep_kernel<<<dim3(BT + 768), dim3(256), 0, stream>>>(x, kadd, xb, Wq, Wk, Wv, Wt);
    qkv_mfma<<<dim3(UU / 128, BT / 128, 3), dim3(256), 0, stream>>>(
        xb, Wt, bq, bk, bv, Qb, Kb, Vt);
    attn_mfma<<<dim3(32, BB * HH), dim3(256), 0, stream>>>(Qb, Kb, Vt, kadd, Ob);
    ln_kernel<<<dim3(BT), dim3(256), 0, stream>>>(Ob, x, gamma, beta, out);
}